// Round 3
// baseline (23.627 us; speedup 1.0000x reference)
//
#include <hip/hip_runtime.h>
#include <math.h>

#define NBINS 512
#define K1_THREADS 512

// Single fused kernel: one thread per gaussian. Walk only the active bin
// range [blo, bhi] (pdf == 0 left of the zero crossing due to the lower
// clamp; < 6e-13 beyond 7.5 sigma; upper clamp provably never binds:
// 0.4*cf + 0.61*(1-cf) < 1). Scatter into a per-block LDS histogram with
// ds_add_f32, then flush PRE-SCALED (x 1/r^2, linearity) partials straight
// into d_out with global_atomic_add_f32 — no second kernel, no partial
// round-trip.
__global__ __launch_bounds__(K1_THREADS) void gauss_scatter_fused(
    const float* __restrict__ means,
    const float* __restrict__ scan_point,
    const float* __restrict__ colours,
    const float* __restrict__ coefficients,
    const float* __restrict__ opacities,
    const float* __restrict__ pre_act,
    const int*   __restrict__ view_id_p,
    float* __restrict__ out,   // NBINS floats, zeroed by memset node
    int n)
{
    __shared__ float hist[NBINS];
    const int tid = threadIdx.x;
    hist[tid] = 0.0f;
    __syncthreads();

    const int i = blockIdx.x * K1_THREADS + tid;
    if (i < n) {
        const int vid = view_id_p[0];
        const float op  = opacities[i + vid];      // (N,1)[:, view_id]
        const float col = colours[i];
        const float inten = (1.0f / (1.0f + __expf(-op))) * col * col;
        const float cf    = 1.0f / (1.0f + __expf(-coefficients[i]));

        const float dx = means[3*i]   - scan_point[0];
        const float dy = means[3*i+1] - scan_point[1];
        const float dz = means[3*i+2] - scan_point[2];
        const float r0 = sqrtf(fmaf(dx, dx, fmaf(dy, dy, dz*dz)));

        const float sigma = fmaxf(__expf(pre_act[i]), 0.005f);

        // e = (r - r0) * q, with q chosen so g = exp2(-e^2)
        const float q  = 0.8493218002880191f / sigma;  // sqrt(0.5*log2(e))/sigma
        const float c  = inten * 0.005f;               // fold intensity + BIN_RES/2
        const float A2 = c * cf * 0.3989422804014327f / sigma;
        const float B3 = c * (1.0f - cf) / (0.8493218002880191f * sigma);

        // active range: pdf >= 0 for r >= r0 - (cf/(1-cf))*0.39894*sigma,
        // negligible for r > r0 + 7.5*sigma. r_[b] = 0.005*(b+1).
        const float rlo = r0 - (cf / (1.0f - cf)) * 0.3989422804014327f * sigma;
        const float rhi = r0 + 7.5f * sigma;
        int blo = (int)ceilf(rlo * 200.0f - 1.0f);
        int bhi = (int)floorf(rhi * 200.0f - 1.0f);
        blo = max(blo, 0);
        bhi = min(bhi, NBINS - 1);

        float e = (0.005f * (float)(blo + 1) - r0) * q;
        const float de = 0.005f * q;
        for (int b = blo; b <= bhi; ++b) {
            const float g = __builtin_amdgcn_exp2f(-(e * e));
            const float t = g * fmaf(B3, e, A2);   // inten*pr
            unsafeAtomicAdd(&hist[b], t);          // ds_add_f32
            e += de;
        }
    }
    __syncthreads();

    // Pre-scaled flush: out[b] += hist[b] / r_b^2  (sum-then-scale ==
    // scale-then-sum by linearity). One global f32 atomic per thread.
    const float v = hist[tid];
    if (v != 0.0f) {
        const float r = 0.005f * (float)(tid + 1);
        unsafeAtomicAdd(&out[tid], v / (r * r));
    }
}

extern "C" void kernel_launch(void* const* d_in, const int* in_sizes, int n_in,
                              void* d_out, int out_size, void* d_ws, size_t ws_size,
                              hipStream_t stream) {
    const float* means        = (const float*)d_in[0];
    const float* scan_point   = (const float*)d_in[1];
    const float* colours      = (const float*)d_in[2];
    const float* coefficients = (const float*)d_in[3];
    const float* opacities    = (const float*)d_in[4];
    const float* pre_act      = (const float*)d_in[5];
    const int*   view_id      = (const int*)d_in[6];

    const int n = in_sizes[2];                         // colours has N elements
    const int G = (n + K1_THREADS - 1) / K1_THREADS;   // 256 for N=131072

    float* out = (float*)d_out;

    // d_out is poisoned once before timing and never re-zeroed between
    // replays — zero it every call (graph-capturable memset node).
    hipMemsetAsync(out, 0, NBINS * sizeof(float), stream);

    gauss_scatter_fused<<<G, K1_THREADS, 0, stream>>>(
        means, scan_point, colours, coefficients, opacities, pre_act,
        view_id, out, n);
}